// Round 14
// baseline (39.460 us; speedup 1.0000x reference)
//
#include <hip/hip_runtime.h>

#define B_ 8
#define N_ 2048
#define F_ 128

typedef __attribute__((ext_vector_type(8))) short short8v;
typedef __attribute__((ext_vector_type(4))) float f32x4;

__device__ inline short f2bf(float f) {
    union { float f; unsigned u; } c; c.f = f;
    unsigned r = (c.u + 0x7FFFu + ((c.u >> 16) & 1u)) >> 16;
    return (short)r;
}

// Zero-sync column-split GCN: 64 blocks = 8 batches x 8 col-tiles(16).
// Each block owns ALL 2048 rows of its batch for 16 output columns ->
// every cross-row reduction (A, s0, s1) is block-local. No workspace.
// b = bid&7: with round-robin dispatch, all 8 blocks of batch b land on
// XCD b and share x[b] (1 MB) in that XCD's L2 (perf-only heuristic).
__global__ __launch_bounds__(512, 1) void gcn_cs(
    const float* __restrict__ x, const float* __restrict__ adj_w,
    const float* __restrict__ adj_b_p, const float* __restrict__ weight,
    const float* __restrict__ bias, float* __restrict__ outx)
{
    __shared__ unsigned short wt[16 * 128];   // W^T bf16 (this block's 16 cols), swizzled
    __shared__ float adjw[256];
    __shared__ float aw[2048], ajw[2048], disr[2048], ajdr[2048];
    __shared__ float sred0[128], sred1[128];
    __shared__ float apart[8];

    const int bid = blockIdx.x;                 // 0..63
    const int b = bid & 7, ct = bid >> 3;
    const int c0 = ct * 16;
    const int t = threadIdx.x;                  // 0..511
    const int w = t >> 6, lane = t & 63;        // 8 waves
    const int u = lane & 15, g = lane >> 4;
    const int rb = w * 256;                     // wave's row range: rb..rb+255
    const float adjb = adj_b_p[0];

    if (t < 256) adjw[t] = adj_w[t];
    // stage W^T bf16: wt[cc][slot] with slot = kb ^ cc (proven swizzle)
    if (t < 256) {
        const int cc = t >> 4, kb = t & 15;
        short8v v;
        #pragma unroll
        for (int e = 0; e < 8; ++e)
            v[e] = f2bf(weight[(kb * 8 + e) * F_ + c0 + cc]);
        *reinterpret_cast<short8v*>(&wt[cc * 128 + (kb ^ cc) * 8]) = v;
    }
    __syncthreads();

    // B-fragments live in registers for the whole GEMM (col = u)
    short8v bW[4];
    #pragma unroll
    for (int kk = 0; kk < 4; ++kk)
        bW[kk] = *reinterpret_cast<const short8v*>(&wt[u * 128 + (((kk << 2) + g) ^ u) * 8]);

    f32x4 acc[16];
    #pragma unroll
    for (int i = 0; i < 16; ++i) acc[i] = (f32x4)(0.f);

    // ---- main loop: 16 row-tiles of 16; lane -> row rb+i*16+u, k-slice g*8
    #pragma unroll
    for (int i = 0; i < 16; ++i) {
        const int row = rb + i * 16 + u;
        const float* xr = x + (size_t)(b * N_ + row) * F_;
        float4 X[8];
        #pragma unroll
        for (int kk = 0; kk < 4; ++kk) {
            X[kk * 2]     = *reinterpret_cast<const float4*>(xr + kk * 32 + g * 8);
            X[kk * 2 + 1] = *reinterpret_cast<const float4*>(xr + kk * 32 + g * 8 + 4);
        }
        // f32-exact a_i/a_j partial for this row (k-slice), reduced over g
        float ai = 0.f, aj = 0.f;
        #pragma unroll
        for (int kk = 0; kk < 4; ++kk) {
            const float* xp = reinterpret_cast<const float*>(&X[kk * 2]);
            #pragma unroll
            for (int e = 0; e < 8; ++e) {
                const int k = kk * 32 + g * 8 + e;
                ai = fmaf(xp[e], adjw[k], ai);
                aj = fmaf(xp[e], adjw[128 + k], aj);
            }
        }
        ai += __shfl_xor(ai, 16, 64); ai += __shfl_xor(ai, 32, 64);
        aj += __shfl_xor(aj, 16, 64); aj += __shfl_xor(aj, 32, 64);
        if (g == 0) { aw[row] = ai; ajw[row] = aj; }
        // MFMA: acc[i] over the 16x16 out-tile
        #pragma unroll
        for (int kk = 0; kk < 4; ++kk) {
            const float* xp = reinterpret_cast<const float*>(&X[kk * 2]);
            short8v af;
            #pragma unroll
            for (int e = 0; e < 8; ++e) af[e] = f2bf(xp[e]);
            acc[i] = __builtin_amdgcn_mfma_f32_16x16x32_bf16(af, bW[kk], acc[i], 0, 0, 0);
        }
    }
    __syncthreads();

    // ---- A = sum over all 2048 a_j (block-local)
    {
        const float4 a4 = *reinterpret_cast<const float4*>(&ajw[t * 4]);
        float s = (a4.x + a4.y) + (a4.z + a4.w);
        #pragma unroll
        for (int off = 32; off > 0; off >>= 1) s += __shfl_down(s, off, 64);
        if (lane == 0) apart[w] = s;
    }
    __syncthreads();
    float Atot = 0.f;
    #pragma unroll
    for (int q = 0; q < 8; ++q) Atot += apart[q];

    // ---- dis / a_j*dis per row (thread -> 4 rows)
    {
        const float4 a4 = *reinterpret_cast<const float4*>(&aw[t * 4]);
        const float4 j4 = *reinterpret_cast<const float4*>(&ajw[t * 4]);
        const float av[4] = {a4.x, a4.y, a4.z, a4.w};
        const float jv[4] = {j4.x, j4.y, j4.z, j4.w};
        float dv[4], jdv[4];
        #pragma unroll
        for (int e = 0; e < 4; ++e) {
            const float deg = fmaxf(2048.f * (av[e] + adjb) + Atot + 1.f, 1.f);
            dv[e] = rsqrtf(deg);
            jdv[e] = jv[e] * dv[e];
        }
        float4 d4, jd4;
        d4.x = dv[0]; d4.y = dv[1]; d4.z = dv[2]; d4.w = dv[3];
        jd4.x = jdv[0]; jd4.y = jdv[1]; jd4.z = jdv[2]; jd4.w = jdv[3];
        *reinterpret_cast<float4*>(&disr[t * 4]) = d4;
        *reinterpret_cast<float4*>(&ajdr[t * 4]) = jd4;
    }
    __syncthreads();

    // ---- s0/s1 for this block's 16 cols (block-local over all 2048 rows)
    {
        float s0 = 0.f, s1 = 0.f;
        #pragma unroll
        for (int i = 0; i < 16; ++i) {
            #pragma unroll
            for (int r = 0; r < 4; ++r) {
                const int row = rb + i * 16 + g * 4 + r;
                s0 = fmaf(disr[row], acc[i][r], s0);
                s1 = fmaf(ajdr[row], acc[i][r], s1);
            }
        }
        s0 += __shfl_xor(s0, 16, 64); s0 += __shfl_xor(s0, 32, 64);
        s1 += __shfl_xor(s1, 16, 64); s1 += __shfl_xor(s1, 32, 64);
        if (g == 0) { sred0[w * 16 + u] = s0; sred1[w * 16 + u] = s1; }
    }
    __syncthreads();
    float s0f = 0.f, s1f = 0.f;
    #pragma unroll
    for (int q = 0; q < 8; ++q) {
        s0f += sred0[q * 16 + u];
        s1f += sred1[q * 16 + u];
    }
    const float bl = bias[c0 + u];

    // ---- epilogue: single out write (col c0+u, rows of this wave)
    #pragma unroll
    for (int i = 0; i < 16; ++i) {
        #pragma unroll
        for (int r = 0; r < 4; ++r) {
            const int row = rb + i * 16 + g * 4 + r;
            const float d = disr[row];
            const float ab = aw[row] + adjb;
            const float o = fmaxf(d * (ab * s0f + s1f + d * acc[i][r]) + bl, 0.f);
            outx[(size_t)(b * N_ + row) * F_ + c0 + u] = o;
        }
    }
}

extern "C" void kernel_launch(void* const* d_in, const int* in_sizes, int n_in,
                              void* d_out, int out_size, void* d_ws, size_t ws_size,
                              hipStream_t stream) {
    const float* x      = (const float*)d_in[0];
    const float* adj_w  = (const float*)d_in[1];
    const float* adj_b  = (const float*)d_in[2];
    const float* weight = (const float*)d_in[3];
    const float* bias   = (const float*)d_in[4];
    float* out = (float*)d_out;

    gcn_cs<<<64, 512, 0, stream>>>(x, adj_w, adj_b, weight, bias, out);
}

// Round 15
// 30.785 us; speedup vs baseline: 1.2818x; 1.2818x over previous
//
#include <hip/hip_runtime.h>

#define N_ 2048
#define F_ 128

// workspace (u64 units)
#define WS_P1 0      // [8*128]       tagged per-block a_j partial sums
#define WS_SF 1024   // [8*256]       tagged finals per (batch, cv)
#define WS_P2 3072   // [8][128][256] tagged s-partials: P2[(b*128+kb)*256 + cv]

typedef __attribute__((ext_vector_type(8))) short short8v;
typedef __attribute__((ext_vector_type(4))) float f32x4;
typedef unsigned long long u64;

__device__ inline short f2bf(float f) {
    union { float f; unsigned u; } c; c.f = f;
    unsigned r = (c.u + 0x7FFFu + ((c.u >> 16) & 1u)) >> 16;
    return (short)r;
}
__device__ inline void store_pair(u64* p, float f) {
    union { float f; unsigned u; } c; c.f = f;
    const u64 v = ((u64)(~c.u) << 32) | (u64)c.u;
    __hip_atomic_store(p, v, __ATOMIC_RELAXED, __HIP_MEMORY_SCOPE_AGENT);
}
__device__ inline bool pair_ok(u64 v) {
    return (unsigned)(v >> 32) == (unsigned)(~(unsigned)v);
}
__device__ inline float pair_val(u64 v) {
    union { unsigned u; float f; } c; c.u = (unsigned)v;
    return c.f;
}
__device__ inline u64 spin_load(u64* p) {
    u64 v = __hip_atomic_load(p, __ATOMIC_RELAXED, __HIP_MEMORY_SCOPE_AGENT);
    while (!pair_ok(v)) {
        __builtin_amdgcn_s_sleep(2);
        v = __hip_atomic_load(p, __ATOMIC_RELAXED, __HIP_MEMORY_SCOPE_AGENT);
    }
    return v;
}

// DEADLOCK RULE (r8): producers contiguous in blockIdx (b = bid>>7).
// LAYOUT RULE (r9): bulk publishes/gathers wave-coalesced.
// OCCUPANCY LEVER (r15): 1024 blocks @ 4/CU = 16 waves/CU -> spins on one
// block overlap with compute of 3 co-resident blocks.
__global__ __launch_bounds__(256, 4) void gcn_one(
    const float* __restrict__ x, const float* __restrict__ adj_w,
    const float* __restrict__ adj_b_p, const float* __restrict__ weight,
    const float* __restrict__ bias, float* __restrict__ outx,
    u64* __restrict__ P1, u64* __restrict__ SF, u64* __restrict__ P2)
{
    __shared__ unsigned short wt[128 * 128];   // W^T bf16, slot-swizzled (32 KB)
    __shared__ float adjw[256];
    __shared__ float ail[16], ajl[16], disl[16], ajdl[16];
    __shared__ float s0l[128], s1l[128], bl[128];
    __shared__ float Ash;

    const int bid = blockIdx.x;                 // 0..1023
    const int b = bid >> 7;                     // contiguous producer chunks
    const int kbme = bid & 127;                 // 0..127
    const int r0 = kbme * 16;
    const int t = threadIdx.x;                  // 0..255
    const int lane = t & 63, w = t >> 6;        // 4 waves
    const int u = lane & 15, g = lane >> 4;

    const float adjb = adj_b_p[0];
    adjw[t] = adj_w[t];
    if (t < 128) bl[t] = bias[t];
    __syncthreads();

    // ---- phase 1: every wave loads the SAME 16 rows (r0+u), k-slice g*8
    const float* xrow = x + (size_t)(b * N_ + r0 + u) * F_;
    float4 xa[4], xb[4];
    #pragma unroll
    for (int kk = 0; kk < 4; ++kk) {
        xa[kk] = *reinterpret_cast<const float4*>(xrow + kk * 32 + g * 8);
        xb[kk] = *reinterpret_cast<const float4*>(xrow + kk * 32 + g * 8 + 4);
    }
    // wave 0 alone computes a_i/a_j (other waves' copy would be redundant)
    if (w == 0) {
        float ai = 0.f, aj = 0.f;
        #pragma unroll
        for (int kk = 0; kk < 4; ++kk) {
            const float* pa = reinterpret_cast<const float*>(&xa[kk]);
            const float* pb = reinterpret_cast<const float*>(&xb[kk]);
            #pragma unroll
            for (int e = 0; e < 4; ++e) {
                const int k = kk * 32 + g * 8 + e;
                ai = fmaf(pa[e], adjw[k], ai);
                aj = fmaf(pa[e], adjw[128 + k], aj);
                ai = fmaf(pb[e], adjw[k + 4], ai);
                aj = fmaf(pb[e], adjw[128 + k + 4], aj);
            }
        }
        ai += __shfl_xor(ai, 16, 64); ai += __shfl_xor(ai, 32, 64);
        aj += __shfl_xor(aj, 16, 64); aj += __shfl_xor(aj, 32, 64);
        if (g == 0) { ail[u] = ai + adjb; ajl[u] = aj; }
        // block partial of sum(a_j): reduce over u (all lanes hold row-u value)
        float s = aj;
        s += __shfl_xor(s, 1, 64); s += __shfl_xor(s, 2, 64);
        s += __shfl_xor(s, 4, 64); s += __shfl_xor(s, 8, 64);
        if (lane == 0) store_pair(&P1[b * 128 + kbme], s);
    }

    // ---- stage W^T bf16 (barrier-independent; hides P1 propagation)
    {
        const int cc = t >> 1, kh = (t & 1) * 8;
        #pragma unroll
        for (int j = 0; j < 8; ++j) {
            const int kb = kh + j;
            short8v v;
            #pragma unroll
            for (int e = 0; e < 8; ++e)
                v[e] = f2bf(weight[(kb * 8 + e) * F_ + cc]);
            *reinterpret_cast<short8v*>(&wt[cc * 128 + (kb ^ (cc & 15)) * 8]) = v;
        }
    }
    __syncthreads();

    // ---- MFMA GEMM: wave w covers col-tiles {2w, 2w+1} of its 16 rows
    f32x4 acc[2];
    acc[0] = (f32x4)(0.f); acc[1] = (f32x4)(0.f);
    #pragma unroll
    for (int kk = 0; kk < 4; ++kk) {
        short8v af;
        const float* pa = reinterpret_cast<const float*>(&xa[kk]);
        const float* pb = reinterpret_cast<const float*>(&xb[kk]);
        #pragma unroll
        for (int e = 0; e < 4; ++e) { af[e] = f2bf(pa[e]); af[e + 4] = f2bf(pb[e]); }
        const int kb = kk * 4 + g;
        #pragma unroll
        for (int c = 0; c < 2; ++c) {
            const int col = (w * 2 + c) * 16 + u;
            const short8v bfv = *reinterpret_cast<const short8v*>(&wt[col * 128 + ((kb ^ u)) * 8]);
            acc[c] = __builtin_amdgcn_mfma_f32_16x16x32_bf16(af, bfv, acc[c], 0, 0, 0);
        }
    }

    // ---- barrier A: 128 tagged partials; t<64 polls two each
    if (t < 64) {
        float s = pair_val(spin_load(&P1[b * 128 + t]))
                + pair_val(spin_load(&P1[b * 128 + 64 + t]));
        #pragma unroll
        for (int off = 32; off > 0; off >>= 1) s += __shfl_down(s, off, 64);
        if (t == 0) Ash = s;
    }
    __syncthreads();
    if (t < 16) {
        const float deg = fmaxf(2048.f * ail[t] + Ash + 1.f, 1.f);
        const float d = rsqrtf(deg);
        disl[t] = d;
        ajdl[t] = ajl[t] * d;
    }
    __syncthreads();

    // ---- s-partials from MFMA accumulators; publish (each col unique per wave)
    #pragma unroll
    for (int c = 0; c < 2; ++c) {
        float s0 = 0.f, s1 = 0.f;
        #pragma unroll
        for (int r = 0; r < 4; ++r) {
            const int row = g * 4 + r;
            s0 = fmaf(disl[row], acc[c][r], s0);
            s1 = fmaf(ajdl[row], acc[c][r], s1);
        }
        s0 += __shfl_xor(s0, 16, 64); s0 += __shfl_xor(s0, 32, 64);
        s1 += __shfl_xor(s1, 16, 64); s1 += __shfl_xor(s1, 32, 64);
        if (g == 0) {
            const int col = (w * 2 + c) * 16 + u;
            const size_t base = (size_t)(b * 128 + kbme) * 256;
            store_pair(&P2[base + col], s0);
            store_pair(&P2[base + 128 + col], s1);
        }
    }

    // ---- stage 2: waves 0,1 finalize cv = kbme*2 + w (128 partials each)
    if (w < 2) {
        const int cv = kbme * 2 + w;
        float s = pair_val(spin_load(&P2[(size_t)(b * 128 + lane) * 256 + cv]))
                + pair_val(spin_load(&P2[(size_t)(b * 128 + 64 + lane) * 256 + cv]));
        #pragma unroll
        for (int off = 32; off > 0; off >>= 1) s += __shfl_down(s, off, 64);
        if (lane == 0) store_pair(&SF[b * 256 + cv], s);
    }

    // ---- stage 3: thread t polls final t
    {
        const float sv = pair_val(spin_load(&SF[b * 256 + t]));
        if (t < 128) s0l[t] = sv; else s1l[t - 128] = sv;
    }
    __syncthreads();

    // ---- epilogue on MFMA accumulators, single out write
    #pragma unroll
    for (int c = 0; c < 2; ++c) {
        const int col = (w * 2 + c) * 16 + u;
        const float sv0 = s0l[col], sv1 = s1l[col], bv = bl[col];
        #pragma unroll
        for (int r = 0; r < 4; ++r) {
            const int row = g * 4 + r;
            const float d = disl[row], ab = ail[row];
            const float o = fmaxf(d * (ab * sv0 + sv1 + d * acc[c][r]) + bv, 0.f);
            outx[(size_t)(b * N_ + r0 + row) * F_ + col] = o;
        }
    }
}

extern "C" void kernel_launch(void* const* d_in, const int* in_sizes, int n_in,
                              void* d_out, int out_size, void* d_ws, size_t ws_size,
                              hipStream_t stream) {
    const float* x      = (const float*)d_in[0];
    const float* adj_w  = (const float*)d_in[1];
    const float* adj_b  = (const float*)d_in[2];
    const float* weight = (const float*)d_in[3];
    const float* bias   = (const float*)d_in[4];
    float* out = (float*)d_out;
    u64* ws = (u64*)d_ws;

    gcn_one<<<1024, 256, 0, stream>>>(x, adj_w, adj_b, weight, bias, out,
                                      ws + WS_P1, ws + WS_SF, ws + WS_P2);
}

// Round 16
// 18.223 us; speedup vs baseline: 2.1654x; 1.6894x over previous
//
#include <hip/hip_runtime.h>

#define N_ 2048
#define F_ 128

// workspace (u64 units)
#define WS_P1 0      // [8*64]          tagged per-block a_j partial sums
#define WS_SF 512    // [8*256]         tagged finals per (batch, cv)  (cv = 2c+vec)
#define WS_P2 2560   // [8][64][256]    tagged s-partials: P2[(b*64+kb)*256 + cv]
                     //  kb-major: stage-1 publish is wave-coalesced (r9 lesson)

typedef __attribute__((ext_vector_type(8))) short short8v;
typedef __attribute__((ext_vector_type(4))) float f32x4;
typedef unsigned long long u64;

__device__ inline short f2bf(float f) {
    union { float f; unsigned u; } c; c.f = f;
    unsigned r = (c.u + 0x7FFFu + ((c.u >> 16) & 1u)) >> 16;
    return (short)r;
}
__device__ inline void store_pair(u64* p, float f) {
    union { float f; unsigned u; } c; c.f = f;
    const u64 v = ((u64)(~c.u) << 32) | (u64)c.u;
    __hip_atomic_store(p, v, __ATOMIC_RELAXED, __HIP_MEMORY_SCOPE_AGENT);
}
__device__ inline bool pair_ok(u64 v) {
    return (unsigned)(v >> 32) == (unsigned)(~(unsigned)v);
}
__device__ inline float pair_val(u64 v) {
    union { unsigned u; float f; } c; c.u = (unsigned)v;
    return c.f;
}

// DEADLOCK RULE (r8): spin producer sets contiguous in blockIdx (b = bid>>6).
// LAYOUT RULE (r9): publishes and gathers must be wave-coalesced.
// TREE RULE (r6→r12): reduction hops only if maximally parallel —
// every block finalizes 4 cv with exactly 1 record per thread.
// CONFIG OPTIMUM (r15 map): 512 blocks x 256 thr @ 2/CU; 1024 and 256 both lose.
__global__ __launch_bounds__(256, 2) void gcn_one(
    const float* __restrict__ x, const float* __restrict__ adj_w,
    const float* __restrict__ adj_b_p, const float* __restrict__ weight,
    const float* __restrict__ bias, float* __restrict__ outx,
    u64* __restrict__ P1, u64* __restrict__ SF, u64* __restrict__ P2)
{
    __shared__ unsigned short wt[128 * 128];   // W^T bf16, slot-swizzled (32 KB)
    __shared__ float adjw[256];
    __shared__ float ail[32], ajl[32], disl[32], ajdl[32];
    __shared__ float red0[2][128], red1[2][128];
    __shared__ float s0l[128], s1l[128], bl[128];
    __shared__ float Ash;

    const int bid = blockIdx.x;                 // 0..511
    const int b = bid >> 6;                     // contiguous producer chunks
    const int kbme = bid & 63;                  // 0..63
    const int r0 = kbme * 32;
    const int t = threadIdx.x;                  // 0..255
    const int lane = t & 63, w = t >> 6;        // 4 waves
    const int u = lane & 15, g = lane >> 4;
    const int wr = (w & 1) * 16;                // row-group (0 or 16)
    const int ct0 = (w >> 1) * 4;               // col-tile base (0 or 4)

    const float adjb = adj_b_p[0];
    adjw[t] = adj_w[t];
    if (t < 128) bl[t] = bias[t];
    __syncthreads();

    // ---- phase 1: read x ONCE in MFMA A-layout; a_i/a_j via in-lane + shfl
    const float* xrow = x + (size_t)(b * N_ + r0 + wr + u) * F_;
    float4 xa[4], xb[4];
    #pragma unroll
    for (int kk = 0; kk < 4; ++kk) {
        xa[kk] = *reinterpret_cast<const float4*>(xrow + kk * 32 + g * 8);
        xb[kk] = *reinterpret_cast<const float4*>(xrow + kk * 32 + g * 8 + 4);
    }
    {
        float ai = 0.f, aj = 0.f;
        #pragma unroll
        for (int kk = 0; kk < 4; ++kk) {
            const float va[4] = {xa[kk].x, xa[kk].y, xa[kk].z, xa[kk].w};
            const float vb[4] = {xb[kk].x, xb[kk].y, xb[kk].z, xb[kk].w};
            #pragma unroll
            for (int i = 0; i < 4; ++i) {
                const int k = kk * 32 + g * 8 + i;
                ai = fmaf(va[i], adjw[k], ai);
                aj = fmaf(va[i], adjw[128 + k], aj);
                ai = fmaf(vb[i], adjw[k + 4], ai);
                aj = fmaf(vb[i], adjw[128 + k + 4], aj);
            }
        }
        ai += __shfl_xor(ai, 16, 64); ai += __shfl_xor(ai, 32, 64);
        aj += __shfl_xor(aj, 16, 64); aj += __shfl_xor(aj, 32, 64);
        if (w < 2 && g == 0) {
            ail[wr + u] = ai + adjb;
            ajl[wr + u] = aj;
        }
    }
    __syncthreads();
    // publish tagged a_j partial ASAP
    if (t < 32) {
        float s = ajl[t];
        #pragma unroll
        for (int off = 16; off > 0; off >>= 1) s += __shfl_down(s, off, 64);
        if (t == 0) store_pair(&P1[b * 64 + kbme], s);
    }

    // ---- stage W^T bf16 (barrier-independent; hides P1 propagation)
    {
        const int c = t & 127, khalf = t >> 7;
        for (int j8 = 0; j8 < 8; ++j8) {
            const int kb = khalf * 8 + j8;
            short8v v;
            #pragma unroll
            for (int i = 0; i < 8; ++i)
                v[i] = f2bf(weight[(kb * 8 + i) * F_ + c]);
            const int slot = kb ^ (c & 15);
            *reinterpret_cast<short8v*>(&wt[c * 128 + slot * 8]) = v;
        }
    }
    __syncthreads();

    // ---- MFMA GEMM from registers (still barrier-independent)
    f32x4 acc[4];
    #pragma unroll
    for (int i = 0; i < 4; ++i) acc[i] = (f32x4)(0.f);
    #pragma unroll
    for (int kk = 0; kk < 4; ++kk) {
        short8v af;
        af[0] = f2bf(xa[kk].x); af[1] = f2bf(xa[kk].y);
        af[2] = f2bf(xa[kk].z); af[3] = f2bf(xa[kk].w);
        af[4] = f2bf(xb[kk].x); af[5] = f2bf(xb[kk].y);
        af[6] = f2bf(xb[kk].z); af[7] = f2bf(xb[kk].w);
        const int kb = kk * 4 + g;
        #pragma unroll
        for (int c = 0; c < 4; ++c) {
            const int col = (ct0 + c) * 16 + u;
            const int slot = kb ^ u;            // col&15 == u
            const short8v bfv = *reinterpret_cast<const short8v*>(&wt[col * 128 + slot * 8]);
            acc[c] = __builtin_amdgcn_mfma_f32_16x16x32_bf16(af, bfv, acc[c], 0, 0, 0);
        }
    }

    // ---- barrier A: spin on the 64 tagged P1 partials of this batch
    if (t < 64) {
        u64 v;
        while (true) {
            v = __hip_atomic_load(&P1[b * 64 + t], __ATOMIC_RELAXED, __HIP_MEMORY_SCOPE_AGENT);
            if (pair_ok(v)) break;
            __builtin_amdgcn_s_sleep(1);
        }
        float s = pair_val(v);
        #pragma unroll
        for (int off = 32; off > 0; off >>= 1) s += __shfl_down(s, off, 64);
        if (t == 0) Ash = s;
    }
    __syncthreads();
    if (t < 32) {
        const float deg = fmaxf(2048.f * ail[t] + Ash + 1.f, 1.f);
        const float d = rsqrtf(deg);
        disl[t] = d;
        ajdl[t] = ajl[t] * d;
    }
    __syncthreads();

    // ---- s-partials DIRECTLY from MFMA accumulators
    #pragma unroll
    for (int c = 0; c < 4; ++c) {
        float s0 = 0.f, s1 = 0.f;
        #pragma unroll
        for (int r = 0; r < 4; ++r) {
            const int row = wr + g * 4 + r;
            s0 = fmaf(disl[row], acc[c][r], s0);
            s1 = fmaf(ajdl[row], acc[c][r], s1);
        }
        s0 += __shfl_xor(s0, 16, 64); s0 += __shfl_xor(s0, 32, 64);
        s1 += __shfl_xor(s1, 16, 64); s1 += __shfl_xor(s1, 32, 64);
        if (g == 0) {
            red0[w & 1][(ct0 + c) * 16 + u] = s0;
            red1[w & 1][(ct0 + c) * 16 + u] = s1;
        }
    }
    __syncthreads();
    // ---- stage 1 publish: all 256 threads, coalesced (cv = t, c = t>>1)
    {
        const int c = t >> 1;
        const float v = (t & 1) ? (red1[0][c] + red1[1][c])
                                : (red0[0][c] + red0[1][c]);
        store_pair(&P2[(size_t)(b * 64 + kbme) * 256 + t], v);
    }

    // ---- stage 2: this block finalizes cv = kbme*4 + w (1 record per thread)
    {
        const int cv = kbme * 4 + w;
        u64 v;
        while (true) {
            v = __hip_atomic_load(&P2[(size_t)(b * 64 + lane) * 256 + cv],
                                  __ATOMIC_RELAXED, __HIP_MEMORY_SCOPE_AGENT);
            if (pair_ok(v)) break;
            __builtin_amdgcn_s_sleep(1);
        }
        float s = pair_val(v);
        #pragma unroll
        for (int off = 32; off > 0; off >>= 1) s += __shfl_down(s, off, 64);
        if (lane == 0) store_pair(&SF[b * 256 + cv], s);
    }

    // ---- stage 3: spin on the 256 finals (2 KB), land in s0l/s1l
    {
        u64 v;
        while (true) {
            v = __hip_atomic_load(&SF[b * 256 + t], __ATOMIC_RELAXED, __HIP_MEMORY_SCOPE_AGENT);
            if (pair_ok(v)) break;
            __builtin_amdgcn_s_sleep(1);
        }
        const float sv = pair_val(v);
        if ((t & 1) == 0) s0l[t >> 1] = sv; else s1l[t >> 1] = sv;
    }
    __syncthreads();

    // ---- epilogue on MFMA accumulators, single out write
    #pragma unroll
    for (int c = 0; c < 4; ++c) {
        const int col = (ct0 + c) * 16 + u;
        const float sv0 = s0l[col], sv1 = s1l[col], bv = bl[col];
        #pragma unroll
        for (int r = 0; r < 4; ++r) {
            const int row = wr + g * 4 + r;
            const float d = disl[row], ab = ail[row];
            const float o = fmaxf(d * (ab * sv0 + sv1 + d * acc[c][r]) + bv, 0.f);
            outx[(size_t)(b * N_ + r0 + row) * F_ + col] = o;
        }
    }
}

extern "C" void kernel_launch(void* const* d_in, const int* in_sizes, int n_in,
                              void* d_out, int out_size, void* d_ws, size_t ws_size,
                              hipStream_t stream) {
    const float* x      = (const float*)d_in[0];
    const float* adj_w  = (const float*)d_in[1];
    const float* adj_b  = (const float*)d_in[2];
    const float* weight = (const float*)d_in[3];
    const float* bias   = (const float*)d_in[4];
    float* out = (float*)d_out;
    u64* ws = (u64*)d_ws;

    gcn_one<<<512, 256, 0, stream>>>(x, adj_w, adj_b, weight, bias, out,
                                     ws + WS_P1, ws + WS_SF, ws + WS_P2);
}